// Round 1
// baseline (2164.023 us; speedup 1.0000x reference)
//
#include <hip/hip_runtime.h>
#include <hip/hip_bf16.h>

#define DI __device__ __forceinline__

typedef unsigned short u16;
typedef unsigned int u32;
typedef __attribute__((ext_vector_type(8))) short bf16x8;   // 8 bf16 in 4 VGPRs
typedef __attribute__((ext_vector_type(4))) float f32x4;

// ---- model constants ----
#define B_   2
#define T_   2048
#define D_   1024
#define H_   16
#define KH_  4
#define HD_  64
#define F_   4096
#define L_   4
#define V_   32000
#define M_   (B_ * T_)          // 4096 tokens
#define QKVN (H_*HD_ + 2*KH_*HD_)  // 1536

DI u16 f2bf(float f) {
  __hip_bfloat16 h = __float2bfloat16(f);
  return *reinterpret_cast<u16*>(&h);
}

DI void gl_lds16(const void* g, void* l) {
  __builtin_amdgcn_global_load_lds(
      (const __attribute__((address_space(1))) u32*)g,
      (__attribute__((address_space(3))) u32*)l, 16, 0, 0);
}

// ---------------- embedding: x = embed[ids] + pos ----------------
__global__ __launch_bounds__(256) void embed_kernel(const int* __restrict__ ids,
                                                    const float* __restrict__ ew,
                                                    const float* __restrict__ pw,
                                                    float* __restrict__ x) {
  const int row = blockIdx.x;          // 0..4095
  const int t = row & (T_ - 1);
  const int id = ids[row];
  float4 e = reinterpret_cast<const float4*>(ew + (size_t)id * D_)[threadIdx.x];
  float4 p = reinterpret_cast<const float4*>(pw + (size_t)t * D_)[threadIdx.x];
  e.x += p.x; e.y += p.y; e.z += p.z; e.w += p.w;
  reinterpret_cast<float4*>(x + (size_t)row * D_)[threadIdx.x] = e;
}

// ---------------- f32 -> bf16 elementwise (embed table) ----------------
__global__ __launch_bounds__(256) void conv_kernel(const float* __restrict__ W,
                                                   u16* __restrict__ Wb) {
  const size_t i = (size_t)blockIdx.x * 256 + threadIdx.x;   // float4 index
  float4 v = reinterpret_cast<const float4*>(W)[i];
  ushort4 ov;
  ov.x = f2bf(v.x); ov.y = f2bf(v.y); ov.z = f2bf(v.z); ov.w = f2bf(v.w);
  reinterpret_cast<ushort4*>(Wb)[i] = ov;
}

// ---------------- transpose + convert: W[K][N] f32 -> Wt[N][K] bf16 ----------------
__global__ __launch_bounds__(256) void convt_kernel(const float* __restrict__ W,
                                                    u16* __restrict__ Wt,
                                                    int K, int N) {
  __shared__ float t[32][33];
  const int k0 = blockIdx.x * 32, n0 = blockIdx.y * 32;
  const int tx = threadIdx.x & 31, ty = threadIdx.x >> 5;   // ty: 0..7
  #pragma unroll
  for (int i = 0; i < 4; i++)
    t[ty + i*8][tx] = W[(size_t)(k0 + ty + i*8) * N + n0 + tx];
  __syncthreads();
  #pragma unroll
  for (int i = 0; i < 4; i++)
    Wt[(size_t)(n0 + ty + i*8) * K + k0 + tx] = f2bf(t[tx][ty + i*8]);
}

// ---------------- RMSNorm: f32 in -> bf16 out ----------------
__global__ __launch_bounds__(256) void rmsnorm_kernel(const float* __restrict__ x,
                                                      const float* __restrict__ w,
                                                      u16* __restrict__ out) {
  const int row = blockIdx.x;
  const int tid = threadIdx.x;
  float4 v = reinterpret_cast<const float4*>(x + (size_t)row * D_)[tid];
  float ss = v.x*v.x + v.y*v.y + v.z*v.z + v.w*v.w;
  #pragma unroll
  for (int off = 32; off > 0; off >>= 1) ss += __shfl_down(ss, off, 64);
  __shared__ float red[4];
  if ((tid & 63) == 0) red[tid >> 6] = ss;
  __syncthreads();
  const float tot = red[0] + red[1] + red[2] + red[3];
  const float rstd = rsqrtf(tot * (1.0f / D_) + 1e-6f);
  float4 wv = reinterpret_cast<const float4*>(w)[tid];
  ushort4 ov;
  ov.x = f2bf(v.x * rstd * wv.x);
  ov.y = f2bf(v.y * rstd * wv.y);
  ov.z = f2bf(v.z * rstd * wv.z);
  ov.w = f2bf(v.w * rstd * wv.w);
  reinterpret_cast<ushort4*>(out + (size_t)row * D_)[tid] = ov;
}

// ---------------- GEMM: C[M][N] = A[M][K] * Bt[N][K]^T  (m97 structure) ----------------
// EPI: 0 = bf16 out, 1 = f32 out + residual add, 2 = exact GELU -> bf16, 3 = f32 out
template <int EPI>
__global__ __launch_bounds__(256) void gemm_bt(const u16* __restrict__ A,
                                               const u16* __restrict__ Bt,
                                               const float* __restrict__ res,
                                               u16* __restrict__ Cb,
                                               float* __restrict__ Cf,
                                               int M, int N, int K) {
  __shared__ u16 As[128 * 64];
  __shared__ u16 Bs[128 * 64];
  const int tid = threadIdx.x;
  const int n0 = blockIdx.x * 128;
  const int m0 = blockIdx.y * 128;
  const int lane = tid & 63, wave = tid >> 6;
  const int wm = wave >> 1, wn = wave & 1;
  const int l15 = lane & 15, l4 = lane >> 4;
  const int srow = tid >> 3, scol = (tid & 7) * 8;
  const u16* ag = A + (size_t)(m0 + srow) * K + scol;
  const u16* bg = Bt + (size_t)(n0 + srow) * K + scol;
  u16* asd = &As[srow * 64 + scol];   // == 16B * tid : linear in lane for gl_lds
  u16* bsd = &Bs[srow * 64 + scol];
  f32x4 acc[4][4] = {};
  const int nk = K >> 6;
  for (int kt = 0; kt < nk; kt++) {
    const int k0 = kt * 64;
    __syncthreads();
    #pragma unroll
    for (int i = 0; i < 4; i++) gl_lds16(ag + (size_t)i*32*K + k0, asd + i*32*64);
    #pragma unroll
    for (int i = 0; i < 4; i++) gl_lds16(bg + (size_t)i*32*K + k0, bsd + i*32*64);
    __syncthreads();
    #pragma unroll
    for (int s = 0; s < 2; s++) {
      bf16x8 af[4], bfv[4];
      #pragma unroll
      for (int i = 0; i < 4; i++)
        af[i] = *reinterpret_cast<const bf16x8*>(&As[(wm*64 + i*16 + l15)*64 + s*32 + l4*8]);
      #pragma unroll
      for (int j = 0; j < 4; j++)
        bfv[j] = *reinterpret_cast<const bf16x8*>(&Bs[(wn*64 + j*16 + l15)*64 + s*32 + l4*8]);
      #pragma unroll
      for (int i = 0; i < 4; i++)
        #pragma unroll
        for (int j = 0; j < 4; j++)
          acc[i][j] = __builtin_amdgcn_mfma_f32_16x16x32_bf16(af[i], bfv[j], acc[i][j], 0, 0, 0);
    }
  }
  #pragma unroll
  for (int i = 0; i < 4; i++) {
    #pragma unroll
    for (int j = 0; j < 4; j++) {
      #pragma unroll
      for (int r = 0; r < 4; r++) {
        const int row = m0 + wm*64 + i*16 + l4*4 + r;
        const int col = n0 + wn*64 + j*16 + l15;
        const size_t idx = (size_t)row * N + col;
        const float v = acc[i][j][r];
        if (EPI == 0) {
          Cb[idx] = f2bf(v);
        } else if (EPI == 1) {
          Cf[idx] = v + res[idx];
        } else if (EPI == 2) {
          const float g = 0.5f * v * (1.0f + erff(v * 0.70710678118f));
          Cb[idx] = f2bf(g);
        } else {
          Cf[idx] = v;
        }
      }
    }
  }
}

// ---------------- flash attention (causal, GQA) ----------------
// grid: (T/64, H, B); block 256 = 4 waves; wave w owns q rows [qt*64+w*16, +16)
__global__ __launch_bounds__(256) void attn_kernel(const u16* __restrict__ qkv,
                                                   u16* __restrict__ o) {
  const int qt = blockIdx.x;
  const int h  = blockIdx.y;
  const int b  = blockIdx.z;
  const int kh = h / (H_ / KH_);
  __shared__ u16 Ks[64 * 64];
  __shared__ u16 Vt[64 * 72];       // V transposed [d][k], stride 72 (bank-friendly)
  __shared__ u16 Pl[4][16 * 72];    // per-wave P tile [q][k]
  const int tid = threadIdx.x, lane = tid & 63, wave = tid >> 6;
  const int l15 = lane & 15, l4 = lane >> 4;
  const size_t Mrow = (size_t)b * T_;

  bf16x8 qf[2];
  {
    const u16* qp = qkv + (Mrow + qt*64 + wave*16 + l15) * QKVN + h*HD_ + l4*8;
    qf[0] = *reinterpret_cast<const bf16x8*>(qp);
    qf[1] = *reinterpret_cast<const bf16x8*>(qp + 32);
  }
  float m_run[4], l_run[4];
  f32x4 oacc[4] = {};
  #pragma unroll
  for (int r = 0; r < 4; r++) { m_run[r] = -1e30f; l_run[r] = 0.0f; }

  const int srow = tid >> 3, scol = (tid & 7) * 8;
  for (int kt = 0; kt <= qt; kt++) {
    const u16* kg = qkv + (Mrow + kt*64 + srow) * QKVN + D_ + kh*HD_ + scol;
    const u16* vg = kg + KH_*HD_;
    __syncthreads();                     // prev-iter readers done
    gl_lds16(kg, &Ks[srow*64 + scol]);
    gl_lds16(kg + 32*QKVN, &Ks[(srow+32)*64 + scol]);
    {
      bf16x8 v0 = *reinterpret_cast<const bf16x8*>(vg);
      bf16x8 v1 = *reinterpret_cast<const bf16x8*>(vg + 32*QKVN);
      #pragma unroll
      for (int j = 0; j < 8; j++) {
        Vt[(scol + j)*72 + srow]      = (u16)v0[j];
        Vt[(scol + j)*72 + srow + 32] = (u16)v1[j];
      }
    }
    __syncthreads();                     // staging visible (drains vmcnt too)

    // S = Q K^T * scale
    f32x4 sa[4] = {};
    #pragma unroll
    for (int s = 0; s < 2; s++)
      #pragma unroll
      for (int n = 0; n < 4; n++) {
        bf16x8 kf = *reinterpret_cast<const bf16x8*>(&Ks[(n*16 + l15)*64 + s*32 + l4*8]);
        sa[n] = __builtin_amdgcn_mfma_f32_16x16x32_bf16(qf[s], kf, sa[n], 0, 0, 0);
      }
    #pragma unroll
    for (int n = 0; n < 4; n++)
      #pragma unroll
      for (int r = 0; r < 4; r++) sa[n][r] *= 0.125f;
    if (kt == qt) {                      // diagonal tile: causal mask
      const int qloc = wave*16 + l4*4;
      #pragma unroll
      for (int n = 0; n < 4; n++) {
        const int kloc = n*16 + l15;
        #pragma unroll
        for (int r = 0; r < 4; r++)
          if (kloc > qloc + r) sa[n][r] = -1e30f;
      }
    }
    // online softmax (row = q; reduce across 16 lanes sharing l4)
    float mx[4];
    #pragma unroll
    for (int r = 0; r < 4; r++)
      mx[r] = fmaxf(fmaxf(sa[0][r], sa[1][r]), fmaxf(sa[2][r], sa[3][r]));
    #pragma unroll
    for (int off = 1; off < 16; off <<= 1)
      #pragma unroll
      for (int r = 0; r < 4; r++)
        mx[r] = fmaxf(mx[r], __shfl_xor(mx[r], off, 64));
    float alpha[4], rs[4];
    #pragma unroll
    for (int r = 0; r < 4; r++) {
      const float nm = fmaxf(m_run[r], mx[r]);
      alpha[r] = __expf(m_run[r] - nm);
      m_run[r] = nm;
      rs[r] = 0.0f;
    }
    u16* pw = &Pl[wave][0];
    #pragma unroll
    for (int n = 0; n < 4; n++)
      #pragma unroll
      for (int r = 0; r < 4; r++) {
        const float p = __expf(sa[n][r] - m_run[r]);
        rs[r] += p;
        pw[(l4*4 + r)*72 + n*16 + l15] = f2bf(p);
      }
    #pragma unroll
    for (int off = 1; off < 16; off <<= 1)
      #pragma unroll
      for (int r = 0; r < 4; r++)
        rs[r] += __shfl_xor(rs[r], off, 64);
    #pragma unroll
    for (int r = 0; r < 4; r++) l_run[r] = l_run[r]*alpha[r] + rs[r];
    #pragma unroll
    for (int n = 0; n < 4; n++)
      #pragma unroll
      for (int r = 0; r < 4; r++) oacc[n][r] *= alpha[r];

    asm volatile("s_waitcnt lgkmcnt(0)" ::: "memory");  // in-wave P write -> read
    // O += P V
    #pragma unroll
    for (int s = 0; s < 2; s++) {
      bf16x8 pa = *reinterpret_cast<const bf16x8*>(&Pl[wave][l15*72 + s*32 + l4*8]);
      #pragma unroll
      for (int n = 0; n < 4; n++) {
        bf16x8 vb = *reinterpret_cast<const bf16x8*>(&Vt[(n*16 + l15)*72 + s*32 + l4*8]);
        oacc[n] = __builtin_amdgcn_mfma_f32_16x16x32_bf16(pa, vb, oacc[n], 0, 0, 0);
      }
    }
  }
  #pragma unroll
  for (int n = 0; n < 4; n++)
    #pragma unroll
    for (int r = 0; r < 4; r++) {
      const float ov = oacc[n][r] / l_run[r];
      const size_t row = Mrow + qt*64 + wave*16 + l4*4 + r;
      o[row * (size_t)(H_*HD_) + h*HD_ + n*16 + l15] = f2bf(ov);
    }
}

// ---------------- workspace layout ----------------
#define OFF_X     0ull                     // f32  [4096][1024]   16.78 MB
#define OFF_H     16777216ull              // bf16 [4096][1024]    8.39 MB
#define OFF_QKV   25165824ull              // bf16 [4096][1536]   12.58 MB
#define OFF_O     37748736ull              // bf16 [4096][1024]    8.39 MB
#define OFF_U     46137344ull              // bf16 [4096][4096]   33.55 MB
#define OFF_WTQ   79691776ull              // bf16 [1536][1024]    3.15 MB
#define OFF_WTO   82837504ull              // bf16 [1024][1024]    2.10 MB
#define OFF_WT1   84934656ull              // bf16 [4096][1024]    8.39 MB
#define OFF_WT2   93323264ull              // bf16 [1024][4096]    8.39 MB
#define OFF_EBF   101711872ull             // bf16 [32000][1024]  65.54 MB
// total ~167.2 MB

extern "C" void kernel_launch(void* const* d_in, const int* in_sizes, int n_in,
                              void* d_out, int out_size, void* d_ws, size_t ws_size,
                              hipStream_t stream) {
  const int*   ids = (const int*)  d_in[0];
  const float* ew  = (const float*)d_in[1];
  const float* pw  = (const float*)d_in[2];
  const float* ln1 = (const float*)d_in[3];
  const float* ln2 = (const float*)d_in[4];
  const float* wq  = (const float*)d_in[5];
  const float* wkv = (const float*)d_in[6];
  const float* wo  = (const float*)d_in[7];
  const float* w1  = (const float*)d_in[8];
  const float* w2  = (const float*)d_in[9];
  const float* nw  = (const float*)d_in[10];
  float* out = (float*)d_out;

  char* ws = (char*)d_ws;
  float* x   = (float*)(ws + OFF_X);
  u16*   h   = (u16*)  (ws + OFF_H);
  u16*   qkv = (u16*)  (ws + OFF_QKV);
  u16*   o   = (u16*)  (ws + OFF_O);
  u16*   u   = (u16*)  (ws + OFF_U);
  u16*   wtq = (u16*)  (ws + OFF_WTQ);
  u16*   wto = (u16*)  (ws + OFF_WTO);
  u16*   wt1 = (u16*)  (ws + OFF_WT1);
  u16*   wt2 = (u16*)  (ws + OFF_WT2);
  u16*   ebf = (u16*)  (ws + OFF_EBF);

  embed_kernel<<<M_, 256, 0, stream>>>(ids, ew, pw, x);
  conv_kernel<<<(V_*D_/4)/256, 256, 0, stream>>>(ew, ebf);

  for (int l = 0; l < L_; l++) {
    convt_kernel<<<dim3(32, 32),  256, 0, stream>>>(wq  + (size_t)l*D_*(H_*HD_), wtq, D_, H_*HD_);
    convt_kernel<<<dim3(32, 16),  256, 0, stream>>>(wkv + (size_t)l*D_*(2*KH_*HD_), wtq + (size_t)(H_*HD_)*D_, D_, 2*KH_*HD_);
    convt_kernel<<<dim3(32, 32),  256, 0, stream>>>(wo  + (size_t)l*(H_*HD_)*D_, wto, H_*HD_, D_);
    convt_kernel<<<dim3(32, 128), 256, 0, stream>>>(w1  + (size_t)l*D_*F_, wt1, D_, F_);
    convt_kernel<<<dim3(128, 32), 256, 0, stream>>>(w2  + (size_t)l*F_*D_, wt2, F_, D_);

    rmsnorm_kernel<<<M_, 256, 0, stream>>>(x, ln1 + (size_t)l*D_, h);
    gemm_bt<0><<<dim3(QKVN/128, M_/128), 256, 0, stream>>>(h, wtq, nullptr, qkv, nullptr, M_, QKVN, D_);
    attn_kernel<<<dim3(T_/64, H_, B_), 256, 0, stream>>>(qkv, o);
    gemm_bt<1><<<dim3(D_/128, M_/128), 256, 0, stream>>>(o, wto, x, nullptr, x, M_, D_, H_*HD_);
    rmsnorm_kernel<<<M_, 256, 0, stream>>>(x, ln2 + (size_t)l*D_, h);
    gemm_bt<2><<<dim3(F_/128, M_/128), 256, 0, stream>>>(h, wt1, nullptr, u, nullptr, M_, F_, D_);
    gemm_bt<1><<<dim3(D_/128, M_/128), 256, 0, stream>>>(u, wt2, x, nullptr, x, M_, D_, F_);
  }

  rmsnorm_kernel<<<M_, 256, 0, stream>>>(x, nw, h);
  gemm_bt<3><<<dim3(V_/128, M_/128), 256, 0, stream>>>(h, ebf, nullptr, nullptr, out, M_, V_, D_);
}

// Round 3
// 1965.743 us; speedup vs baseline: 1.1009x; 1.1009x over previous
//
#include <hip/hip_runtime.h>
#include <hip/hip_bf16.h>

#define DI __device__ __forceinline__

typedef unsigned short u16;
typedef unsigned int u32;
typedef __attribute__((ext_vector_type(8))) short bf16x8;   // 8 bf16 in 4 VGPRs
typedef __attribute__((ext_vector_type(4))) float f32x4;

// ---- model constants ----
#define B_   2
#define T_   2048
#define D_   1024
#define H_   16
#define KH_  4
#define HD_  64
#define F_   4096
#define L_   4
#define V_   32000
#define M_   (B_ * T_)          // 4096 tokens
#define QKVN (H_*HD_ + 2*KH_*HD_)  // 1536

DI u16 f2bf(float f) {
  __hip_bfloat16 h = __float2bfloat16(f);
  return *reinterpret_cast<u16*>(&h);
}

DI void gl_lds16(const void* g, void* l) {
  __builtin_amdgcn_global_load_lds(
      (const __attribute__((address_space(1))) u32*)g,
      (__attribute__((address_space(3))) u32*)l, 16, 0, 0);
}

#define BARRIER() do { asm volatile("" ::: "memory"); __builtin_amdgcn_s_barrier(); asm volatile("" ::: "memory"); } while (0)
#define LGK0()    asm volatile("s_waitcnt lgkmcnt(0)" ::: "memory")
#define VMC(n)    asm volatile("s_waitcnt vmcnt(" #n ")" ::: "memory")
#define PRIO(p)   __builtin_amdgcn_s_setprio(p)

// ---------------- embedding: x = embed[ids] + pos ----------------
__global__ __launch_bounds__(256) void embed_kernel(const int* __restrict__ ids,
                                                    const float* __restrict__ ew,
                                                    const float* __restrict__ pw,
                                                    float* __restrict__ x) {
  const int row = blockIdx.x;          // 0..4095
  const int t = row & (T_ - 1);
  const int id = ids[row];
  float4 e = reinterpret_cast<const float4*>(ew + (size_t)id * D_)[threadIdx.x];
  float4 p = reinterpret_cast<const float4*>(pw + (size_t)t * D_)[threadIdx.x];
  e.x += p.x; e.y += p.y; e.z += p.z; e.w += p.w;
  reinterpret_cast<float4*>(x + (size_t)row * D_)[threadIdx.x] = e;
}

// ---------------- f32 -> bf16 elementwise (embed table) ----------------
__global__ __launch_bounds__(256) void conv_kernel(const float* __restrict__ W,
                                                   u16* __restrict__ Wb) {
  const size_t i = (size_t)blockIdx.x * 256 + threadIdx.x;   // float4 index
  float4 v = reinterpret_cast<const float4*>(W)[i];
  ushort4 ov;
  ov.x = f2bf(v.x); ov.y = f2bf(v.y); ov.z = f2bf(v.z); ov.w = f2bf(v.w);
  reinterpret_cast<ushort4*>(Wb)[i] = ov;
}

// ---------------- transpose + convert: W[K][N] f32 -> Wt[N][K] bf16 ----------------
__global__ __launch_bounds__(256) void convt_kernel(const float* __restrict__ W,
                                                    u16* __restrict__ Wt,
                                                    int K, int N) {
  __shared__ float t[32][33];
  const int k0 = blockIdx.x * 32, n0 = blockIdx.y * 32;
  const int tx = threadIdx.x & 31, ty = threadIdx.x >> 5;   // ty: 0..7
  #pragma unroll
  for (int i = 0; i < 4; i++)
    t[ty + i*8][tx] = W[(size_t)(k0 + ty + i*8) * N + n0 + tx];
  __syncthreads();
  #pragma unroll
  for (int i = 0; i < 4; i++)
    Wt[(size_t)(n0 + ty + i*8) * K + k0 + tx] = f2bf(t[tx][ty + i*8]);
}

// ---------------- RMSNorm: f32 in -> bf16 out ----------------
__global__ __launch_bounds__(256) void rmsnorm_kernel(const float* __restrict__ x,
                                                      const float* __restrict__ w,
                                                      u16* __restrict__ out) {
  const int row = blockIdx.x;
  const int tid = threadIdx.x;
  float4 v = reinterpret_cast<const float4*>(x + (size_t)row * D_)[tid];
  float ss = v.x*v.x + v.y*v.y + v.z*v.z + v.w*v.w;
  #pragma unroll
  for (int off = 32; off > 0; off >>= 1) ss += __shfl_down(ss, off, 64);
  __shared__ float red[4];
  if ((tid & 63) == 0) red[tid >> 6] = ss;
  __syncthreads();
  const float tot = red[0] + red[1] + red[2] + red[3];
  const float rstd = rsqrtf(tot * (1.0f / D_) + 1e-6f);
  float4 wv = reinterpret_cast<const float4*>(w)[tid];
  ushort4 ov;
  ov.x = f2bf(v.x * rstd * wv.x);
  ov.y = f2bf(v.y * rstd * wv.y);
  ov.z = f2bf(v.z * rstd * wv.z);
  ov.w = f2bf(v.w * rstd * wv.w);
  reinterpret_cast<ushort4*>(out + (size_t)row * D_)[tid] = ov;
}

// ---------------- GEMM 128x128 (m97 structure) ----------------
// EPI: 0 = bf16 out, 1 = f32 out + residual add, 2 = exact GELU -> bf16, 3 = f32 out
template <int EPI>
__global__ __launch_bounds__(256) void gemm_bt(const u16* __restrict__ A,
                                               const u16* __restrict__ Bt,
                                               const float* __restrict__ res,
                                               u16* __restrict__ Cb,
                                               float* __restrict__ Cf,
                                               int M, int N, int K) {
  __shared__ u16 As[128 * 64];
  __shared__ u16 Bs[128 * 64];
  const int tid = threadIdx.x;
  const int n0 = blockIdx.x * 128;
  const int m0 = blockIdx.y * 128;
  const int lane = tid & 63, wave = tid >> 6;
  const int wm = wave >> 1, wn = wave & 1;
  const int l15 = lane & 15, l4 = lane >> 4;
  const int srow = tid >> 3, scol = (tid & 7) * 8;
  const u16* ag = A + (size_t)(m0 + srow) * K + scol;
  const u16* bg = Bt + (size_t)(n0 + srow) * K + scol;
  u16* asd = &As[srow * 64 + scol];
  u16* bsd = &Bs[srow * 64 + scol];
  f32x4 acc[4][4] = {};
  const int nk = K >> 6;
  for (int kt = 0; kt < nk; kt++) {
    const int k0 = kt * 64;
    __syncthreads();
    #pragma unroll
    for (int i = 0; i < 4; i++) gl_lds16(ag + (size_t)i*32*K + k0, asd + i*32*64);
    #pragma unroll
    for (int i = 0; i < 4; i++) gl_lds16(bg + (size_t)i*32*K + k0, bsd + i*32*64);
    __syncthreads();
    #pragma unroll
    for (int s = 0; s < 2; s++) {
      bf16x8 af[4], bfv[4];
      #pragma unroll
      for (int i = 0; i < 4; i++)
        af[i] = *reinterpret_cast<const bf16x8*>(&As[(wm*64 + i*16 + l15)*64 + s*32 + l4*8]);
      #pragma unroll
      for (int j = 0; j < 4; j++)
        bfv[j] = *reinterpret_cast<const bf16x8*>(&Bs[(wn*64 + j*16 + l15)*64 + s*32 + l4*8]);
      #pragma unroll
      for (int i = 0; i < 4; i++)
        #pragma unroll
        for (int j = 0; j < 4; j++)
          acc[i][j] = __builtin_amdgcn_mfma_f32_16x16x32_bf16(af[i], bfv[j], acc[i][j], 0, 0, 0);
    }
  }
  #pragma unroll
  for (int i = 0; i < 4; i++) {
    #pragma unroll
    for (int j = 0; j < 4; j++) {
      #pragma unroll
      for (int r = 0; r < 4; r++) {
        const int row = m0 + wm*64 + i*16 + l4*4 + r;
        const int col = n0 + wn*64 + j*16 + l15;
        const size_t idx = (size_t)row * N + col;
        const float v = acc[i][j][r];
        if (EPI == 0) {
          Cb[idx] = f2bf(v);
        } else if (EPI == 1) {
          Cf[idx] = v + res[idx];
        } else if (EPI == 2) {
          const float g = 0.5f * v * (1.0f + erff(v * 0.70710678118f));
          Cb[idx] = f2bf(g);
        } else {
          Cf[idx] = v;
        }
      }
    }
  }
}

// ---------------- GEMM 256x256, 8-phase counted-vmcnt pipeline (T2+T3+T4+T5) ----
// C[M][N] = A[M][K] * Bt[N][K]^T.  8 waves (2M x 4N), BK=64, 2 K-tiles/iter.
// LDS 128KB: A/B x 2 slots (slot = tile parity). Swizzle: phys colByte =
// logical colByte ^ ((row&7)<<4)  (mask spans BITS 4-6, so the ks*64 bit
// MUST be inside the XOR — that was round-1's bug). global_load_lds dests
// stay linear; global SOURCE is inverse-swizzled (rule 21).
// Phases: p1 i0-3 x j0-1 (reads 8A+4B), p2 i0-3 x j2-3 (4B), p3 i4-7 x j0-1
// (8A), p4 i4-7 x j2-3 (0). Stages lag 4 phases behind first reader;
// vmcnt(6) at p4/p8 = exactly "next slot's 4 half-stages landed".
// EPI: 0 = f32 out, 1 = exact GELU -> bf16
template <int EPI>
__global__ __launch_bounds__(512, 2) void gemm256(const u16* __restrict__ A,
                                                  const u16* __restrict__ Bt,
                                                  u16* __restrict__ Cb,
                                                  float* __restrict__ Cf,
                                                  int M, int N, int K) {
  __shared__ char lds[131072];
  char* const AsB = lds;             // A tiles: slot*32768
  char* const BsB = lds + 65536;     // B tiles: slot*32768
  const int tid = threadIdx.x;
  const int lane = tid & 63, wave = tid >> 6;
  const int wm = wave >> 2, wn = wave & 3;
  const int l15 = lane & 15, l4 = lane >> 4;

  // XCD-chunked, m-fastest block decode (nwg % 8 == 0 for all our shapes)
  const int nm = M >> 8;
  const int nwg = nm * (N >> 8);
  const int cpx = nwg >> 3;
  const int bid = blockIdx.x;
  const int wg = (bid & 7) * cpx + (bid >> 3);
  const int m0 = (wg % nm) << 8;
  const int n0 = (wg / nm) << 8;

  const u16* const Atile = A + (size_t)m0 * K;
  const u16* const Btile = Bt + (size_t)n0 * K;

  // staging: half-tile h (128 rows), per-thread loads j=0,1.
  // phys byte P = h*16384 + j*8192 + tid*16 (linear: wave base + lane*16).
  // logical colByte = physColByte ^ ((row&7)<<4) -> global src offset.
  int soff[2][2], pd[2][2];
  #pragma unroll
  for (int h = 0; h < 2; ++h)
    #pragma unroll
    for (int jj = 0; jj < 2; ++jj) {
      const int row = h*128 + jj*64 + (tid >> 3);
      const int sl  = (tid & 7) ^ (row & 7);
      soff[h][jj] = row * K + sl * 8;             // u16 elements
      pd[h][jj]   = h*16384 + jj*8192 + tid*16;   // bytes
    }
  // read bases (bytes within a 32KB tile buffer) for ks=0,1:
  //   frag (gi,ks): gi*2048 + l15*128 + ((ks*64 + l4*16) ^ ((l15&7)<<4))
  const int swz = (l15 & 7) << 4;
  const int rb0 = l15*128 + ((l4*16)      ^ swz);
  const int rb1 = l15*128 + ((64 + l4*16) ^ swz);

  #define STA(S,H,T) do { const u16* g_ = Atile + (T)*64; char* d_ = AsB + (S)*32768; \
      gl_lds16(g_ + soff[H][0], d_ + pd[H][0]); gl_lds16(g_ + soff[H][1], d_ + pd[H][1]); } while (0)
  #define STB(S,H,T) do { const u16* g_ = Btile + (T)*64; char* d_ = BsB + (S)*32768; \
      gl_lds16(g_ + soff[H][0], d_ + pd[H][0]); gl_lds16(g_ + soff[H][1], d_ + pd[H][1]); } while (0)
  #define RDA(S,GI,RB) (*reinterpret_cast<const bf16x8*>(AsB + (S)*32768 + (GI)*2048 + (RB)))
  #define RDB(S,GJ,RB) (*reinterpret_cast<const bf16x8*>(BsB + (S)*32768 + (GJ)*2048 + (RB)))

  f32x4 acc[8][4] = {};
  bf16x8 Ar[4][2], Br[4][2];

  #define RDA03(S) { _Pragma("unroll") for (int i=0;i<4;++i){ Ar[i][0]=RDA(S,i*2+wm,rb0); Ar[i][1]=RDA(S,i*2+wm,rb1);} }
  #define RDA47(S) { _Pragma("unroll") for (int i=0;i<4;++i){ Ar[i][0]=RDA(S,(i+4)*2+wm,rb0); Ar[i][1]=RDA(S,(i+4)*2+wm,rb1);} }
  #define RDB01(S) { _Pragma("unroll") for (int j=0;j<2;++j){ Br[j][0]=RDB(S,j*4+wn,rb0); Br[j][1]=RDB(S,j*4+wn,rb1);} }
  #define RDB23(S) { _Pragma("unroll") for (int j=2;j<4;++j){ Br[j][0]=RDB(S,j*4+wn,rb0); Br[j][1]=RDB(S,j*4+wn,rb1);} }
  #define MFQ(IO,JL) { _Pragma("unroll") for (int i=0;i<4;++i) _Pragma("unroll") for (int jj=0;jj<2;++jj) { \
      acc[(IO)+i][(JL)+jj] = __builtin_amdgcn_mfma_f32_16x16x32_bf16(Ar[i][0], Br[(JL)+jj][0], acc[(IO)+i][(JL)+jj],0,0,0); \
      acc[(IO)+i][(JL)+jj] = __builtin_amdgcn_mfma_f32_16x16x32_bf16(Ar[i][1], Br[(JL)+jj][1], acc[(IO)+i][(JL)+jj],0,0,0); } }

  // prologue: tile0 (4 halves) + tile1 (all but A-h1, staged by p1 of iter 0)
  STA(0,0,0); STA(0,1,0); STB(0,0,0); STB(0,1,0);
  VMC(4);
  STA(1,0,1); STB(1,0,1); STB(1,1,1);
  VMC(6);
  BARRIER();

  const int niter = K >> 7;    // 2 K-tiles (BK=64) per iteration
  for (int it = 0; it < niter; ++it) {
    const int t0 = it*2, t1 = t0 + 1;
    const bool pf = (it + 1 < niter);
    // ph1: compute slot0 i0-3 x j0-1; stage A-h1(t1) -> slot1
    RDA03(0); RDB01(0); STA(1,1,t1);
    BARRIER(); LGK0(); PRIO(1); MFQ(0,0); PRIO(0); BARRIER();
    // ph2: i0-3 x j2-3; stage A-h0(t0+2) -> slot0
    RDB23(0); if (pf) STA(0,0,t0+2);
    BARRIER(); LGK0(); PRIO(1); MFQ(0,2); PRIO(0); BARRIER();
    // ph3: i4-7 x j0-1; stage B-h0(t0+2)
    RDA47(0); if (pf) STB(0,0,t0+2);
    BARRIER(); LGK0(); PRIO(1); MFQ(4,0); PRIO(0); BARRIER();
    // ph4: i4-7 x j2-3; stage B-h1(t0+2); counted vmcnt
    if (pf) { STB(0,1,t0+2); VMC(6); } else { VMC(0); }
    BARRIER(); PRIO(1); MFQ(4,2); PRIO(0); BARRIER();
    // ph5: compute slot1 i0-3 x j0-1; stage A-h1(t0+2) -> slot0
    RDA03(1); RDB01(1); if (pf) STA(0,1,t0+2);
    BARRIER(); LGK0(); PRIO(1); MFQ(0,0); PRIO(0); BARRIER();
    // ph6: i0-3 x j2-3; stage A-h0(t1+2) -> slot1
    RDB23(1); if (pf) STA(1,0,t1+2);
    BARRIER(); LGK0(); PRIO(1); MFQ(0,2); PRIO(0); BARRIER();
    // ph7: i4-7 x j0-1; stage B-h0(t1+2)
    RDA47(1); if (pf) STB(1,0,t1+2);
    BARRIER(); LGK0(); PRIO(1); MFQ(4,0); PRIO(0); BARRIER();
    // ph8: i4-7 x j2-3; stage B-h1(t1+2); counted vmcnt
    if (pf) { STB(1,1,t1+2); VMC(6); }
    BARRIER(); PRIO(1); MFQ(4,2); PRIO(0); BARRIER();
  }

  // epilogue: C write. row = m0+(i*2+wm)*16+l4*4+r, col = n0+(j*4+wn)*16+l15
  #pragma unroll
  for (int i = 0; i < 8; ++i) {
    const int mrow = m0 + (i*2 + wm)*16 + l4*4;
    #pragma unroll
    for (int j = 0; j < 4; ++j) {
      const int col = n0 + (j*4 + wn)*16 + l15;
      #pragma unroll
      for (int r = 0; r < 4; ++r) {
        const float v = acc[i][j][r];
        const size_t idx = (size_t)(mrow + r) * N + col;
        if (EPI == 0) {
          Cf[idx] = v;
        } else {
          const float g = 0.5f * v * (1.0f + erff(v * 0.70710678118f));
          Cb[idx] = f2bf(g);
        }
      }
    }
  }
  #undef STA
  #undef STB
  #undef RDA
  #undef RDB
  #undef RDA03
  #undef RDA47
  #undef RDB01
  #undef RDB23
  #undef MFQ
}

// ---------------- flash attention (causal, GQA) ----------------
__global__ __launch_bounds__(256) void attn_kernel(const u16* __restrict__ qkv,
                                                   u16* __restrict__ o) {
  const int qt = blockIdx.x;
  const int h  = blockIdx.y;
  const int b  = blockIdx.z;
  const int kh = h / (H_ / KH_);
  __shared__ u16 Ks[64 * 64];
  __shared__ u16 Vt[64 * 72];
  __shared__ u16 Pl[4][16 * 72];
  const int tid = threadIdx.x, lane = tid & 63, wave = tid >> 6;
  const int l15 = lane & 15, l4 = lane >> 4;
  const size_t Mrow = (size_t)b * T_;

  bf16x8 qf[2];
  {
    const u16* qp = qkv + (Mrow + qt*64 + wave*16 + l15) * QKVN + h*HD_ + l4*8;
    qf[0] = *reinterpret_cast<const bf16x8*>(qp);
    qf[1] = *reinterpret_cast<const bf16x8*>(qp + 32);
  }
  float m_run[4], l_run[4];
  f32x4 oacc[4] = {};
  #pragma unroll
  for (int r = 0; r < 4; r++) { m_run[r] = -1e30f; l_run[r] = 0.0f; }

  const int srow = tid >> 3, scol = (tid & 7) * 8;
  for (int kt = 0; kt <= qt; kt++) {
    const u16* kg = qkv + (Mrow + kt*64 + srow) * QKVN + D_ + kh*HD_ + scol;
    const u16* vg = kg + KH_*HD_;
    __syncthreads();
    gl_lds16(kg, &Ks[srow*64 + scol]);
    gl_lds16(kg + 32*QKVN, &Ks[(srow+32)*64 + scol]);
    {
      bf16x8 v0 = *reinterpret_cast<const bf16x8*>(vg);
      bf16x8 v1 = *reinterpret_cast<const bf16x8*>(vg + 32*QKVN);
      #pragma unroll
      for (int j = 0; j < 8; j++) {
        Vt[(scol + j)*72 + srow]      = (u16)v0[j];
        Vt[(scol + j)*72 + srow + 32] = (u16)v1[j];
      }
    }
    __syncthreads();

    f32x4 sa[4] = {};
    #pragma unroll
    for (int s = 0; s < 2; s++)
      #pragma unroll
      for (int n = 0; n < 4; n++) {
        bf16x8 kf = *reinterpret_cast<const bf16x8*>(&Ks[(n*16 + l15)*64 + s*32 + l4*8]);
        sa[n] = __builtin_amdgcn_mfma_f32_16x16x32_bf16(qf[s], kf, sa[n], 0, 0, 0);
      }
    #pragma unroll
    for (int n = 0; n < 4; n++)
      #pragma unroll
      for (int r = 0; r < 4; r++) sa[n][r] *= 0.125f;
    if (kt == qt) {
      const int qloc = wave*16 + l4*4;
      #pragma unroll
      for (int n = 0; n < 4; n++) {
        const int kloc = n*16 + l15;
        #pragma unroll
        for (int r = 0; r < 4; r++)
          if (kloc > qloc + r) sa[n][r] = -1e30f;
      }
    }
    float mx[4];
    #pragma unroll
    for (int r = 0; r < 4; r++)
      mx[r] = fmaxf(fmaxf(sa[0][r], sa[1][r]), fmaxf(sa[2][r], sa[3][r]));
    #pragma unroll
    for (int off = 1; off < 16; off <<= 1)
      #pragma unroll
      for (int r = 0; r < 4; r++)
        mx[r] = fmaxf(mx[r], __shfl_xor(mx[r], off, 64));
    float alpha[4], rs[4];
    #pragma unroll
    for (int r = 0; r < 4; r++) {
      const float nm = fmaxf(m_run[r], mx[r]);
      alpha[r] = __expf(m_run[r] - nm);
      m_run[r] = nm;
      rs[r] = 0.0f;
    }
    u16* pw = &Pl[wave][0];
    #pragma unroll
    for (int n = 0; n < 4; n++)
      #pragma unroll
      for (int r = 0; r < 4; r++) {
        const float p = __expf(sa[n][r] - m_run[r]);
        rs[r] += p;
        pw[(l4*4 + r)*72 + n*16 + l15] = f2bf(p);
      }
    #pragma unroll
    for (int off = 1; off < 16; off <<= 1)
      #pragma unroll
      for (int r = 0; r < 4; r++)
        rs[r] += __shfl_xor(rs[r], off, 64);
    #pragma unroll
    for (int r = 0; r < 4; r++) l_run[r] = l_run[r]*alpha[r] + rs[r];
    #pragma unroll
    for (int n = 0; n < 4; n++)
      #pragma unroll
      for (int r = 0; r < 4; r++) oacc[n][r] *= alpha[r];

    asm volatile("s_waitcnt lgkmcnt(0)" ::: "memory");
    #pragma unroll
    for (int s = 0; s < 2; s++) {
      bf16x8 pa = *reinterpret_cast<const bf16x8*>(&Pl[wave][l15*72 + s*32 + l4*8]);
      #pragma unroll
      for (int n = 0; n < 4; n++) {
        bf16x8 vb = *reinterpret_cast<const bf16x8*>(&Vt[(n*16 + l15)*72 + s*32 + l4*8]);
        oacc[n] = __builtin_amdgcn_mfma_f32_16x16x32_bf16(pa, vb, oacc[n], 0, 0, 0);
      }
    }
  }
  #pragma unroll
  for (int n = 0; n < 4; n++)
    #pragma unroll
    for (int r = 0; r < 4; r++) {
      const float ov = oacc[n][r] / l_run[r];
      const size_t row = Mrow + qt*64 + wave*16 + l4*4 + r;
      o[row * (size_t)(H_*HD_) + h*HD_ + n*16 + l15] = f2bf(ov);
    }
}

// ---------------- workspace layout ----------------
#define OFF_X     0ull
#define OFF_H     16777216ull
#define OFF_QKV   25165824ull
#define OFF_O     37748736ull
#define OFF_U     46137344ull
#define OFF_WTQ   79691776ull
#define OFF_WTO   82837504ull
#define OFF_WT1   84934656ull
#define OFF_WT2   93323264ull
#define OFF_EBF   101711872ull

extern "C" void kernel_launch(void* const* d_in, const int* in_sizes, int n_in,
                              void* d_out, int out_size, void* d_ws, size_t ws_size,
                              hipStream_t stream) {
  const int*   ids = (const int*)  d_in[0];
  const float* ew  = (const float*)d_in[1];
  const float* pw  = (const float*)d_in[2];
  const float* ln1 = (const float*)d_in[3];
  const float* ln2 = (const float*)d_in[4];
  const float* wq  = (const float*)d_in[5];
  const float* wkv = (const float*)d_in[6];
  const float* wo  = (const float*)d_in[7];
  const float* w1  = (const float*)d_in[8];
  const float* w2  = (const float*)d_in[9];
  const float* nw  = (const float*)d_in[10];
  float* out = (float*)d_out;

  char* ws = (char*)d_ws;
  float* x   = (float*)(ws + OFF_X);
  u16*   h   = (u16*)  (ws + OFF_H);
  u16*   qkv = (u16*)  (ws + OFF_QKV);
  u16*   o   = (u16*)  (ws + OFF_O);
  u16*   u   = (u16*)  (ws + OFF_U);
  u16*   wtq = (u16*)  (ws + OFF_WTQ);
  u16*   wto = (u16*)  (ws + OFF_WTO);
  u16*   wt1 = (u16*)  (ws + OFF_WT1);
  u16*   wt2 = (u16*)  (ws + OFF_WT2);
  u16*   ebf = (u16*)  (ws + OFF_EBF);

  embed_kernel<<<M_, 256, 0, stream>>>(ids, ew, pw, x);
  conv_kernel<<<(V_*D_/4)/256, 256, 0, stream>>>(ew, ebf);

  for (int l = 0; l < L_; l++) {
    convt_kernel<<<dim3(32, 32),  256, 0, stream>>>(wq  + (size_t)l*D_*(H_*HD_), wtq, D_, H_*HD_);
    convt_kernel<<<dim3(32, 16),  256, 0, stream>>>(wkv + (size_t)l*D_*(2*KH_*HD_), wtq + (size_t)(H_*HD_)*D_, D_, 2*KH_*HD_);
    convt_kernel<<<dim3(32, 32),  256, 0, stream>>>(wo  + (size_t)l*(H_*HD_)*D_, wto, H_*HD_, D_);
    convt_kernel<<<dim3(32, 128), 256, 0, stream>>>(w1  + (size_t)l*D_*F_, wt1, D_, F_);
    convt_kernel<<<dim3(128, 32), 256, 0, stream>>>(w2  + (size_t)l*F_*D_, wt2, F_, D_);

    rmsnorm_kernel<<<M_, 256, 0, stream>>>(x, ln1 + (size_t)l*D_, h);
    gemm_bt<0><<<dim3(QKVN/128, M_/128), 256, 0, stream>>>(h, wtq, nullptr, qkv, nullptr, M_, QKVN, D_);
    attn_kernel<<<dim3(T_/64, H_, B_), 256, 0, stream>>>(qkv, o);
    gemm_bt<1><<<dim3(D_/128, M_/128), 256, 0, stream>>>(o, wto, x, nullptr, x, M_, D_, H_*HD_);
    rmsnorm_kernel<<<M_, 256, 0, stream>>>(x, ln2 + (size_t)l*D_, h);
    gemm256<1><<<dim3((F_/256)*(M_/256)), 512, 0, stream>>>(h, wt1, u, nullptr, M_, F_, D_);
    gemm_bt<1><<<dim3(D_/128, M_/128), 256, 0, stream>>>(u, wt2, x, nullptr, x, M_, D_, F_);
  }

  rmsnorm_kernel<<<M_, 256, 0, stream>>>(x, nw, h);
  gemm256<0><<<dim3((V_/256)*(M_/256)), 512, 0, stream>>>(h, ebf, nullptr, out, M_, V_, D_);
}

// Round 4
// 1907.750 us; speedup vs baseline: 1.1343x; 1.0304x over previous
//
#include <hip/hip_runtime.h>
#include <hip/hip_bf16.h>

#define DI __device__ __forceinline__

typedef unsigned short u16;
typedef unsigned int u32;
typedef __attribute__((ext_vector_type(8))) short bf16x8;   // 8 bf16 in 4 VGPRs
typedef __attribute__((ext_vector_type(4))) float f32x4;

// ---- model constants ----
#define B_   2
#define T_   2048
#define D_   1024
#define H_   16
#define KH_  4
#define HD_  64
#define F_   4096
#define L_   4
#define V_   32000
#define M_   (B_ * T_)          // 4096 tokens
#define QKVN (H_*HD_ + 2*KH_*HD_)  // 1536

DI u16 f2bf(float f) {
  __hip_bfloat16 h = __float2bfloat16(f);
  return *reinterpret_cast<u16*>(&h);
}

DI void gl_lds16(const void* g, void* l) {
  __builtin_amdgcn_global_load_lds(
      (const __attribute__((address_space(1))) u32*)g,
      (__attribute__((address_space(3))) u32*)l, 16, 0, 0);
}

#define BARRIER() do { asm volatile("" ::: "memory"); __builtin_amdgcn_s_barrier(); asm volatile("" ::: "memory"); } while (0)
#define LGK0()    asm volatile("s_waitcnt lgkmcnt(0)" ::: "memory")
#define VMC(n)    asm volatile("s_waitcnt vmcnt(" #n ")" ::: "memory")
#define PRIO(p)   __builtin_amdgcn_s_setprio(p)

// ---------------- embedding: x = embed[ids] + pos ----------------
__global__ __launch_bounds__(256) void embed_kernel(const int* __restrict__ ids,
                                                    const float* __restrict__ ew,
                                                    const float* __restrict__ pw,
                                                    float* __restrict__ x) {
  const int row = blockIdx.x;          // 0..4095
  const int t = row & (T_ - 1);
  const int id = ids[row];
  float4 e = reinterpret_cast<const float4*>(ew + (size_t)id * D_)[threadIdx.x];
  float4 p = reinterpret_cast<const float4*>(pw + (size_t)t * D_)[threadIdx.x];
  e.x += p.x; e.y += p.y; e.z += p.z; e.w += p.w;
  reinterpret_cast<float4*>(x + (size_t)row * D_)[threadIdx.x] = e;
}

// ---------------- f32 -> bf16 elementwise (embed table) ----------------
__global__ __launch_bounds__(256) void conv_kernel(const float* __restrict__ W,
                                                   u16* __restrict__ Wb) {
  const size_t i = (size_t)blockIdx.x * 256 + threadIdx.x;   // float4 index
  float4 v = reinterpret_cast<const float4*>(W)[i];
  ushort4 ov;
  ov.x = f2bf(v.x); ov.y = f2bf(v.y); ov.z = f2bf(v.z); ov.w = f2bf(v.w);
  reinterpret_cast<ushort4*>(Wb)[i] = ov;
}

// ---------------- fused transpose+convert for one layer's 5 weights ----------
// W[K][N] f32 -> Wt[N][K] bf16, flat grid with compile-time segment table:
//   [0,1024): wq 1024x1024 | [1024,1536): wkv 1024x512 | [1536,2560): wo
//   [2560,6656): w1 1024x4096 | [6656,10752): w2 4096x1024
__global__ __launch_bounds__(256) void convt_fused(const float* __restrict__ wq,
                                                   const float* __restrict__ wkv,
                                                   const float* __restrict__ wo,
                                                   const float* __restrict__ w1,
                                                   const float* __restrict__ w2,
                                                   u16* __restrict__ wtq,
                                                   u16* __restrict__ wto,
                                                   u16* __restrict__ wt1,
                                                   u16* __restrict__ wt2) {
  const int t = blockIdx.x;
  const float* W; u16* Wt; int K, N, local;
  if (t < 1024)      { W = wq;  Wt = wtq;               K = 1024; N = 1024; local = t; }
  else if (t < 1536) { W = wkv; Wt = wtq + 1024*1024;   K = 1024; N = 512;  local = t - 1024; }
  else if (t < 2560) { W = wo;  Wt = wto;               K = 1024; N = 1024; local = t - 1536; }
  else if (t < 6656) { W = w1;  Wt = wt1;               K = 1024; N = 4096; local = t - 2560; }
  else               { W = w2;  Wt = wt2;               K = 4096; N = 1024; local = t - 6656; }
  const int nk = K >> 5;
  const int k0 = (local % nk) * 32, n0 = (local / nk) * 32;
  __shared__ float tb[32][33];
  const int tx = threadIdx.x & 31, ty = threadIdx.x >> 5;   // ty: 0..7
  #pragma unroll
  for (int i = 0; i < 4; i++)
    tb[ty + i*8][tx] = W[(size_t)(k0 + ty + i*8) * N + n0 + tx];
  __syncthreads();
  #pragma unroll
  for (int i = 0; i < 4; i++)
    Wt[(size_t)(n0 + ty + i*8) * K + k0 + tx] = f2bf(tb[tx][ty + i*8]);
}

// ---------------- RMSNorm: f32 in -> bf16 out ----------------
__global__ __launch_bounds__(256) void rmsnorm_kernel(const float* __restrict__ x,
                                                      const float* __restrict__ w,
                                                      u16* __restrict__ out) {
  const int row = blockIdx.x;
  const int tid = threadIdx.x;
  float4 v = reinterpret_cast<const float4*>(x + (size_t)row * D_)[tid];
  float ss = v.x*v.x + v.y*v.y + v.z*v.z + v.w*v.w;
  #pragma unroll
  for (int off = 32; off > 0; off >>= 1) ss += __shfl_down(ss, off, 64);
  __shared__ float red[4];
  if ((tid & 63) == 0) red[tid >> 6] = ss;
  __syncthreads();
  const float tot = red[0] + red[1] + red[2] + red[3];
  const float rstd = rsqrtf(tot * (1.0f / D_) + 1e-6f);
  float4 wv = reinterpret_cast<const float4*>(w)[tid];
  ushort4 ov;
  ov.x = f2bf(v.x * rstd * wv.x);
  ov.y = f2bf(v.y * rstd * wv.y);
  ov.z = f2bf(v.z * rstd * wv.z);
  ov.w = f2bf(v.w * rstd * wv.w);
  reinterpret_cast<ushort4*>(out + (size_t)row * D_)[tid] = ov;
}

// ---------------- GEMM 128x128 (m97 structure) ----------------
// EPI: 0 = bf16 out, 1 = f32 out + residual add
template <int EPI>
__global__ __launch_bounds__(256) void gemm_bt(const u16* __restrict__ A,
                                               const u16* __restrict__ Bt,
                                               const float* __restrict__ res,
                                               u16* __restrict__ Cb,
                                               float* __restrict__ Cf,
                                               int M, int N, int K) {
  __shared__ u16 As[128 * 64];
  __shared__ u16 Bs[128 * 64];
  const int tid = threadIdx.x;
  const int n0 = blockIdx.x * 128;
  const int m0 = blockIdx.y * 128;
  const int lane = tid & 63, wave = tid >> 6;
  const int wm = wave >> 1, wn = wave & 1;
  const int l15 = lane & 15, l4 = lane >> 4;
  const int srow = tid >> 3, scol = (tid & 7) * 8;
  const u16* ag = A + (size_t)(m0 + srow) * K + scol;
  const u16* bg = Bt + (size_t)(n0 + srow) * K + scol;
  u16* asd = &As[srow * 64 + scol];
  u16* bsd = &Bs[srow * 64 + scol];
  f32x4 acc[4][4] = {};
  const int nk = K >> 6;
  for (int kt = 0; kt < nk; kt++) {
    const int k0 = kt * 64;
    __syncthreads();
    #pragma unroll
    for (int i = 0; i < 4; i++) gl_lds16(ag + (size_t)i*32*K + k0, asd + i*32*64);
    #pragma unroll
    for (int i = 0; i < 4; i++) gl_lds16(bg + (size_t)i*32*K + k0, bsd + i*32*64);
    __syncthreads();
    #pragma unroll
    for (int s = 0; s < 2; s++) {
      bf16x8 af[4], bfv[4];
      #pragma unroll
      for (int i = 0; i < 4; i++)
        af[i] = *reinterpret_cast<const bf16x8*>(&As[(wm*64 + i*16 + l15)*64 + s*32 + l4*8]);
      #pragma unroll
      for (int j = 0; j < 4; j++)
        bfv[j] = *reinterpret_cast<const bf16x8*>(&Bs[(wn*64 + j*16 + l15)*64 + s*32 + l4*8]);
      #pragma unroll
      for (int i = 0; i < 4; i++)
        #pragma unroll
        for (int j = 0; j < 4; j++)
          acc[i][j] = __builtin_amdgcn_mfma_f32_16x16x32_bf16(af[i], bfv[j], acc[i][j], 0, 0, 0);
    }
  }
  #pragma unroll
  for (int i = 0; i < 4; i++) {
    #pragma unroll
    for (int j = 0; j < 4; j++) {
      #pragma unroll
      for (int r = 0; r < 4; r++) {
        const int row = m0 + wm*64 + i*16 + l4*4 + r;
        const int col = n0 + wn*64 + j*16 + l15;
        const size_t idx = (size_t)row * N + col;
        const float v = acc[i][j][r];
        if (EPI == 0) {
          Cb[idx] = f2bf(v);
        } else {
          Cf[idx] = v + res[idx];
        }
      }
    }
  }
}

// ---------------- persistent GEMM 256x256, 8-phase counted-vmcnt (K=1024) ----
// C[M][N] = A[M][K] * Bt[N][K]^T, K fixed at 1024 (16 k-tiles, 8 iters/tile).
// Grid = 256 blocks; each owns a contiguous chunk of output tiles (m-fastest
// order -> B-panel L2 reuse). The pipeline NEVER drains across tiles: the
// peeled it=7 iteration's prefetch slots (p2..p8) target the NEXT output
// tile's k-tiles 0/1 with switched base pointers; stage roles and VMC(6)
// counts are identical to steady state (16 k-tiles/tile keeps slot parity).
// C stores issue between tiles with NO wait: they're older than the next 6
// counted loads, so the next p4's VMC(6) drains them, overlapped with p1-p4.
// EPI: 0 = f32 nontemporal out (logits), 1 = exact GELU -> bf16
template <int EPI>
__global__ __launch_bounds__(512, 2) void gemm256p(const u16* __restrict__ A,
                                                   const u16* __restrict__ Bt,
                                                   u16* __restrict__ Cb,
                                                   float* __restrict__ Cf,
                                                   int M, int N) {
  const int K = 1024;
  __shared__ char lds[131072];
  char* const AsB = lds;             // A tiles: slot*32768
  char* const BsB = lds + 65536;     // B tiles: slot*32768
  const int tid = threadIdx.x;
  const int lane = tid & 63, wave = tid >> 6;
  const int wm = wave >> 2, wn = wave & 3;
  const int l15 = lane & 15, l4 = lane >> 4;

  const int nm = M >> 8;
  const int nt_all = nm * (N >> 8);
  const int q = nt_all >> 8, r = nt_all & 255;
  const int b = blockIdx.x;
  const int t_begin = b * q + (b < r ? b : r);
  const int nt = q + (b < r ? 1 : 0);
  const int t_end = t_begin + nt;

  // staging geometry (identical to proven round-2 kernel)
  int soff[2][2], pd[2][2];
  #pragma unroll
  for (int h = 0; h < 2; ++h)
    #pragma unroll
    for (int jj = 0; jj < 2; ++jj) {
      const int row = h*128 + jj*64 + (tid >> 3);
      const int sl  = (tid & 7) ^ (row & 7);
      soff[h][jj] = row * K + sl * 8;             // u16 elements
      pd[h][jj]   = h*16384 + jj*8192 + tid*16;   // bytes
    }
  const int swz = (l15 & 7) << 4;
  const int rb0 = l15*128 + ((l4*16)      ^ swz);
  const int rb1 = l15*128 + ((64 + l4*16) ^ swz);

  #define STA(P,S,H,T) do { const u16* g_ = (P) + (T)*64; char* d_ = AsB + (S)*32768; \
      gl_lds16(g_ + soff[H][0], d_ + pd[H][0]); gl_lds16(g_ + soff[H][1], d_ + pd[H][1]); } while (0)
  #define STB(P,S,H,T) do { const u16* g_ = (P) + (T)*64; char* d_ = BsB + (S)*32768; \
      gl_lds16(g_ + soff[H][0], d_ + pd[H][0]); gl_lds16(g_ + soff[H][1], d_ + pd[H][1]); } while (0)
  #define RDA(S,GI,RB) (*reinterpret_cast<const bf16x8*>(AsB + (S)*32768 + (GI)*2048 + (RB)))
  #define RDB(S,GJ,RB) (*reinterpret_cast<const bf16x8*>(BsB + (S)*32768 + (GJ)*2048 + (RB)))

  f32x4 acc[8][4] = {};
  bf16x8 Ar[4][2], Br[4][2];

  #define RDA03(S) { _Pragma("unroll") for (int i=0;i<4;++i){ Ar[i][0]=RDA(S,i*2+wm,rb0); Ar[i][1]=RDA(S,i*2+wm,rb1);} }
  #define RDA47(S) { _Pragma("unroll") for (int i=0;i<4;++i){ Ar[i][0]=RDA(S,(i+4)*2+wm,rb0); Ar[i][1]=RDA(S,(i+4)*2+wm,rb1);} }
  #define RDB01(S) { _Pragma("unroll") for (int j=0;j<2;++j){ Br[j][0]=RDB(S,j*4+wn,rb0); Br[j][1]=RDB(S,j*4+wn,rb1);} }
  #define RDB23(S) { _Pragma("unroll") for (int j=2;j<4;++j){ Br[j][0]=RDB(S,j*4+wn,rb0); Br[j][1]=RDB(S,j*4+wn,rb1);} }
  #define MFQ(IO,JL) { _Pragma("unroll") for (int i=0;i<4;++i) _Pragma("unroll") for (int jj=0;jj<2;++jj) { \
      acc[(IO)+i][(JL)+jj] = __builtin_amdgcn_mfma_f32_16x16x32_bf16(Ar[i][0], Br[(JL)+jj][0], acc[(IO)+i][(JL)+jj],0,0,0); \
      acc[(IO)+i][(JL)+jj] = __builtin_amdgcn_mfma_f32_16x16x32_bf16(Ar[i][1], Br[(JL)+jj][1], acc[(IO)+i][(JL)+jj],0,0,0); } }

  const u16* Ac = A + (size_t)((t_begin % nm) << 8) * K;
  const u16* Bc = Bt + (size_t)((t_begin / nm) << 8) * K;

  // one-time prologue: tile0 (4 halves) + tile1 minus A-h1 (staged by p1)
  STA(Ac,0,0,0); STA(Ac,0,1,0); STB(Bc,0,0,0); STB(Bc,0,1,0);
  VMC(4);
  STA(Ac,1,0,1); STB(Bc,1,0,1); STB(Bc,1,1,1);
  VMC(6);
  BARRIER();

  for (int t = t_begin; t < t_end; ++t) {
    const bool last = (t + 1 == t_end);
    const u16* An = Ac;
    const u16* Bn = Bc;
    if (!last) {
      const int tn = t + 1;
      An = A + (size_t)((tn % nm) << 8) * K;
      Bn = Bt + (size_t)((tn / nm) << 8) * K;
    }
    // iters 0..6: all prefetch targets within current tile (t0+2 <= 14)
    for (int it = 0; it < 7; ++it) {
      const int t0 = it*2, t1 = t0 + 1;
      RDA03(0); RDB01(0); STA(Ac,1,1,t1);
      BARRIER(); LGK0(); PRIO(1); MFQ(0,0); PRIO(0); BARRIER();
      RDB23(0); STA(Ac,0,0,t0+2);
      BARRIER(); LGK0(); PRIO(1); MFQ(0,2); PRIO(0); BARRIER();
      RDA47(0); STB(Bc,0,0,t0+2);
      BARRIER(); LGK0(); PRIO(1); MFQ(4,0); PRIO(0); BARRIER();
      STB(Bc,0,1,t0+2); VMC(6);
      BARRIER(); PRIO(1); MFQ(4,2); PRIO(0); BARRIER();
      RDA03(1); RDB01(1); STA(Ac,0,1,t0+2);
      BARRIER(); LGK0(); PRIO(1); MFQ(0,0); PRIO(0); BARRIER();
      RDB23(1); STA(Ac,1,0,t1+2);
      BARRIER(); LGK0(); PRIO(1); MFQ(0,2); PRIO(0); BARRIER();
      RDA47(1); STB(Bc,1,0,t1+2);
      BARRIER(); LGK0(); PRIO(1); MFQ(4,0); PRIO(0); BARRIER();
      STB(Bc,1,1,t1+2); VMC(6);
      BARRIER(); PRIO(1); MFQ(4,2); PRIO(0); BARRIER();
    }
    // it = 7 (t0=14, t1=15): prefetch NEXT tile's k-tiles 0/1 (or drain)
    {
      RDA03(0); RDB01(0); STA(Ac,1,1,15);
      BARRIER(); LGK0(); PRIO(1); MFQ(0,0); PRIO(0); BARRIER();
      RDB23(0); if (!last) STA(An,0,0,0);
      BARRIER(); LGK0(); PRIO(1); MFQ(0,2); PRIO(0); BARRIER();
      RDA47(0); if (!last) STB(Bn,0,0,0);
      BARRIER(); LGK0(); PRIO(1); MFQ(4,0); PRIO(0); BARRIER();
      if (!last) { STB(Bn,0,1,0); VMC(6); } else { VMC(0); }
      BARRIER(); PRIO(1); MFQ(4,2); PRIO(0); BARRIER();
      RDA03(1); RDB01(1); if (!last) STA(An,0,1,0);
      BARRIER(); LGK0(); PRIO(1); MFQ(0,0); PRIO(0); BARRIER();
      RDB23(1); if (!last) STA(An,1,0,1);
      BARRIER(); LGK0(); PRIO(1); MFQ(0,2); PRIO(0); BARRIER();
      RDA47(1); if (!last) STB(Bn,1,0,1);
      BARRIER(); LGK0(); PRIO(1); MFQ(4,0); PRIO(0); BARRIER();
      if (!last) { STB(Bn,1,1,1); VMC(6); }
      BARRIER(); PRIO(1); MFQ(4,2); PRIO(0); BARRIER();
    }
    // C write for tile t (no wait; next p4's VMC(6) drains the stores)
    {
      const int m0 = (t % nm) << 8;
      const int n0 = (t / nm) << 8;
      #pragma unroll
      for (int i = 0; i < 8; ++i) {
        const int mrow = m0 + (i*2 + wm)*16 + l4*4;
        #pragma unroll
        for (int j = 0; j < 4; ++j) {
          const int col = n0 + (j*4 + wn)*16 + l15;
          #pragma unroll
          for (int rr = 0; rr < 4; ++rr) {
            const float v = acc[i][j][rr];
            const size_t idx = (size_t)(mrow + rr) * N + col;
            if (EPI == 0) {
              __builtin_nontemporal_store(v, &Cf[idx]);
            } else {
              const float g = 0.5f * v * (1.0f + erff(v * 0.70710678118f));
              Cb[idx] = f2bf(g);
            }
            acc[i][j][rr] = 0.0f;
          }
        }
      }
    }
    Ac = An; Bc = Bn;
  }
  #undef STA
  #undef STB
  #undef RDA
  #undef RDB
  #undef RDA03
  #undef RDA47
  #undef RDB01
  #undef RDB23
  #undef MFQ
}

// ---------------- flash attention (causal, GQA) ----------------
__global__ __launch_bounds__(256) void attn_kernel(const u16* __restrict__ qkv,
                                                   u16* __restrict__ o) {
  const int qt = blockIdx.x;
  const int h  = blockIdx.y;
  const int b  = blockIdx.z;
  const int kh = h / (H_ / KH_);
  __shared__ u16 Ks[64 * 64];
  __shared__ u16 Vt[64 * 72];
  __shared__ u16 Pl[4][16 * 72];
  const int tid = threadIdx.x, lane = tid & 63, wave = tid >> 6;
  const int l15 = lane & 15, l4 = lane >> 4;
  const size_t Mrow = (size_t)b * T_;

  bf16x8 qf[2];
  {
    const u16* qp = qkv + (Mrow + qt*64 + wave*16 + l15) * QKVN + h*HD_ + l4*8;
    qf[0] = *reinterpret_cast<const bf16x8*>(qp);
    qf[1] = *reinterpret_cast<const bf16x8*>(qp + 32);
  }
  float m_run[4], l_run[4];
  f32x4 oacc[4] = {};
  #pragma unroll
  for (int r = 0; r < 4; r++) { m_run[r] = -1e30f; l_run[r] = 0.0f; }

  const int srow = tid >> 3, scol = (tid & 7) * 8;
  for (int kt = 0; kt <= qt; kt++) {
    const u16* kg = qkv + (Mrow + kt*64 + srow) * QKVN + D_ + kh*HD_ + scol;
    const u16* vg = kg + KH_*HD_;
    __syncthreads();
    gl_lds16(kg, &Ks[srow*64 + scol]);
    gl_lds16(kg + 32*QKVN, &Ks[(srow+32)*64 + scol]);
    {
      bf16x8 v0 = *reinterpret_cast<const bf16x8*>(vg);
      bf16x8 v1 = *reinterpret_cast<const bf16x8*>(vg + 32*QKVN);
      #pragma unroll
      for (int j = 0; j < 8; j++) {
        Vt[(scol + j)*72 + srow]      = (u16)v0[j];
        Vt[(scol + j)*72 + srow + 32] = (u16)v1[j];
      }
    }
    __syncthreads();

    f32x4 sa[4] = {};
    #pragma unroll
    for (int s = 0; s < 2; s++)
      #pragma unroll
      for (int n = 0; n < 4; n++) {
        bf16x8 kf = *reinterpret_cast<const bf16x8*>(&Ks[(n*16 + l15)*64 + s*32 + l4*8]);
        sa[n] = __builtin_amdgcn_mfma_f32_16x16x32_bf16(qf[s], kf, sa[n], 0, 0, 0);
      }
    #pragma unroll
    for (int n = 0; n < 4; n++)
      #pragma unroll
      for (int r = 0; r < 4; r++) sa[n][r] *= 0.125f;
    if (kt == qt) {
      const int qloc = wave*16 + l4*4;
      #pragma unroll
      for (int n = 0; n < 4; n++) {
        const int kloc = n*16 + l15;
        #pragma unroll
        for (int r = 0; r < 4; r++)
          if (kloc > qloc + r) sa[n][r] = -1e30f;
      }
    }
    float mx[4];
    #pragma unroll
    for (int r = 0; r < 4; r++)
      mx[r] = fmaxf(fmaxf(sa[0][r], sa[1][r]), fmaxf(sa[2][r], sa[3][r]));
    #pragma unroll
    for (int off = 1; off < 16; off <<= 1)
      #pragma unroll
      for (int r = 0; r < 4; r++)
        mx[r] = fmaxf(mx[r], __shfl_xor(mx[r], off, 64));
    float alpha[4], rs[4];
    #pragma unroll
    for (int r = 0; r < 4; r++) {
      const float nm = fmaxf(m_run[r], mx[r]);
      alpha[r] = __expf(m_run[r] - nm);
      m_run[r] = nm;
      rs[r] = 0.0f;
    }
    u16* pw = &Pl[wave][0];
    #pragma unroll
    for (int n = 0; n < 4; n++)
      #pragma unroll
      for (int r = 0; r < 4; r++) {
        const float p = __expf(sa[n][r] - m_run[r]);
        rs[r] += p;
        pw[(l4*4 + r)*72 + n*16 + l15] = f2bf(p);
      }
    #pragma unroll
    for (int off = 1; off < 16; off <<= 1)
      #pragma unroll
      for (int r = 0; r < 4; r++)
        rs[r] += __shfl_xor(rs[r], off, 64);
    #pragma unroll
    for (int r = 0; r < 4; r++) l_run[r] = l_run[r]*alpha[r] + rs[r];
    #pragma unroll
    for (int n = 0; n < 4; n++)
      #pragma unroll
      for (int r = 0; r < 4; r++) oacc[n][r] *= alpha[r];

    asm volatile("s_waitcnt lgkmcnt(0)" ::: "memory");
    #pragma unroll
    for (int s = 0; s < 2; s++) {
      bf16x8 pa = *reinterpret_cast<const bf16x8*>(&Pl[wave][l15*72 + s*32 + l4*8]);
      #pragma unroll
      for (int n = 0; n < 4; n++) {
        bf16x8 vb = *reinterpret_cast<const bf16x8*>(&Vt[(n*16 + l15)*72 + s*32 + l4*8]);
        oacc[n] = __builtin_amdgcn_mfma_f32_16x16x32_bf16(pa, vb, oacc[n], 0, 0, 0);
      }
    }
  }
  #pragma unroll
  for (int n = 0; n < 4; n++)
    #pragma unroll
    for (int r = 0; r < 4; r++) {
      const float ov = oacc[n][r] / l_run[r];
      const size_t row = Mrow + qt*64 + wave*16 + l4*4 + r;
      o[row * (size_t)(H_*HD_) + h*HD_ + n*16 + l15] = f2bf(ov);
    }
}

// ---------------- workspace layout ----------------
#define OFF_X     0ull
#define OFF_H     16777216ull
#define OFF_QKV   25165824ull
#define OFF_O     37748736ull
#define OFF_U     46137344ull
#define OFF_WTQ   79691776ull
#define OFF_WTO   82837504ull
#define OFF_WT1   84934656ull
#define OFF_WT2   93323264ull
#define OFF_EBF   101711872ull

extern "C" void kernel_launch(void* const* d_in, const int* in_sizes, int n_in,
                              void* d_out, int out_size, void* d_ws, size_t ws_size,
                              hipStream_t stream) {
  const int*   ids = (const int*)  d_in[0];
  const float* ew  = (const float*)d_in[1];
  const float* pw  = (const float*)d_in[2];
  const float* ln1 = (const float*)d_in[3];
  const float* ln2 = (const float*)d_in[4];
  const float* wq  = (const float*)d_in[5];
  const float* wkv = (const float*)d_in[6];
  const float* wo  = (const float*)d_in[7];
  const float* w1  = (const float*)d_in[8];
  const float* w2  = (const float*)d_in[9];
  const float* nw  = (const float*)d_in[10];
  float* out = (float*)d_out;

  char* ws = (char*)d_ws;
  float* x   = (float*)(ws + OFF_X);
  u16*   h   = (u16*)  (ws + OFF_H);
  u16*   qkv = (u16*)  (ws + OFF_QKV);
  u16*   o   = (u16*)  (ws + OFF_O);
  u16*   u   = (u16*)  (ws + OFF_U);
  u16*   wtq = (u16*)  (ws + OFF_WTQ);
  u16*   wto = (u16*)  (ws + OFF_WTO);
  u16*   wt1 = (u16*)  (ws + OFF_WT1);
  u16*   wt2 = (u16*)  (ws + OFF_WT2);
  u16*   ebf = (u16*)  (ws + OFF_EBF);

  embed_kernel<<<M_, 256, 0, stream>>>(ids, ew, pw, x);
  conv_kernel<<<(V_*D_/4)/256, 256, 0, stream>>>(ew, ebf);

  for (int l = 0; l < L_; l++) {
    convt_fused<<<10752, 256, 0, stream>>>(
        wq  + (size_t)l*D_*(H_*HD_),
        wkv + (size_t)l*D_*(2*KH_*HD_),
        wo  + (size_t)l*(H_*HD_)*D_,
        w1  + (size_t)l*D_*F_,
        w2  + (size_t)l*F_*D_,
        wtq, wto, wt1, wt2);

    rmsnorm_kernel<<<M_, 256, 0, stream>>>(x, ln1 + (size_t)l*D_, h);
    gemm_bt<0><<<dim3(QKVN/128, M_/128), 256, 0, stream>>>(h, wtq, nullptr, qkv, nullptr, M_, QKVN, D_);
    attn_kernel<<<dim3(T_/64, H_, B_), 256, 0, stream>>>(qkv, o);
    gemm_bt<1><<<dim3(D_/128, M_/128), 256, 0, stream>>>(o, wto, x, nullptr, x, M_, D_, H_*HD_);
    rmsnorm_kernel<<<M_, 256, 0, stream>>>(x, ln2 + (size_t)l*D_, h);
    gemm256p<1><<<256, 512, 0, stream>>>(h, wt1, u, nullptr, M_, F_);
    gemm_bt<1><<<dim3(D_/128, M_/128), 256, 0, stream>>>(u, wt2, x, nullptr, x, M_, D_, F_);
  }

  rmsnorm_kernel<<<M_, 256, 0, stream>>>(x, nw, h);
  gemm256p<0><<<256, 512, 0, stream>>>(h, ebf, nullptr, out, M_, V_);
}